// Round 8
// baseline (696.401 us; speedup 1.0000x reference)
//
#include <hip/hip_runtime.h>
#include <stdint.h>

#define M_DIM 4096   // BATCH*SEQ
#define N_DIM 16384  // OUT_FEATURES
#define K_DIM 4096   // IN_FEATURES
#define BM 256
#define BN 256
#define BK 64
#define NT (K_DIM / BK)   // 64 K-tiles

typedef __attribute__((ext_vector_type(8))) __bf16 bf16x8;
typedef __attribute__((ext_vector_type(16))) float f32x16;

// fp32 -> bf16 bits, round-to-nearest-even
__device__ __forceinline__ unsigned short f2bf(float f) {
    uint32_t u = __builtin_bit_cast(uint32_t, f);
    uint32_t r = (u + 0x7FFFu + ((u >> 16) & 1u)) >> 16;
    return (unsigned short)r;
}

union Pack8 { unsigned short h[8]; uint4 v; };

__device__ __forceinline__ void async_copy16(const void* g, void* l) {
    __builtin_amdgcn_global_load_lds((__attribute__((address_space(1))) void*)(g),
                                     (__attribute__((address_space(3))) void*)(l),
                                     16, 0, 0);
}

#define BARRIER() do { asm volatile("" ::: "memory"); \
                       __builtin_amdgcn_s_barrier();  \
                       asm volatile("" ::: "memory"); } while (0)

// ---------------- phase 0: cast x fp32 -> bf16 ----------------
__global__ __launch_bounds__(256) void cast_x_kernel(const float* __restrict__ x,
                                                     unsigned short* __restrict__ xb,
                                                     int n8) {
    for (int i = blockIdx.x * blockDim.x + threadIdx.x; i < n8;
         i += gridDim.x * blockDim.x) {
        const float4* p = (const float4*)(x + (size_t)i * 8);
        float4 v0 = p[0], v1 = p[1];
        Pack8 o;
        o.h[0] = f2bf(v0.x); o.h[1] = f2bf(v0.y);
        o.h[2] = f2bf(v0.z); o.h[3] = f2bf(v0.w);
        o.h[4] = f2bf(v1.x); o.h[5] = f2bf(v1.y);
        o.h[6] = f2bf(v1.z); o.h[7] = f2bf(v1.w);
        *(uint4*)(xb + (size_t)i * 8) = o.v;
    }
}

// ---------------- phase 1: dequant weights -> bf16 ----------------
__global__ __launch_bounds__(256) void dequant_kernel(const int* __restrict__ stored,
                                                      const int* __restrict__ sign,
                                                      const float* __restrict__ log_min,
                                                      const float* __restrict__ log_max,
                                                      unsigned short* __restrict__ wb,
                                                      int n8) {
    const float lmin = log_min[0];
    const float lrange = log_max[0] - lmin;
    for (int i = blockIdx.x * blockDim.x + threadIdx.x; i < n8;
         i += gridDim.x * blockDim.x) {
        const int4* ps = (const int4*)(stored + (size_t)i * 8);
        const int4* pg = (const int4*)(sign + (size_t)i * 8);
        int4 s0 = ps[0], s1 = ps[1];
        int4 g0 = pg[0], g1 = pg[1];
        int sv[8] = {s0.x, s0.y, s0.z, s0.w, s1.x, s1.y, s1.z, s1.w};
        int gv[8] = {g0.x, g0.y, g0.z, g0.w, g1.x, g1.y, g1.z, g1.w};
        Pack8 o;
#pragma unroll
        for (int j = 0; j < 8; ++j) {
            float nrm = (255.0f - (float)sv[j]) * (1.0f / 254.0f);
            float w = __expf(lmin + nrm * lrange);
            o.h[j] = f2bf(gv[j] ? w : -w);
        }
        *(uint4*)(wb + (size_t)i * 8) = o.v;
    }
}

// ---------------- phase 2: 256x256 bf16 GEMM, 32x32x16 MFMA, hoisted addressing ----------------
// A: [M][K] bf16, W: [N][K] bf16, C: [M][N] fp32
// LDS 128 KiB: dbuf c at c*65536: A.h0/A.h1/B.h0/B.h1 at u*16384 (128 rows x 128 B).
// Swizzle involution: byte ^= ((row&7)<<4); global_load_lds dest linear, global
// SOURCE pre-inverse-swizzled, same XOR applied on ds_read addresses (rule #21).
//
// Fragment map (32x32x16): A/B lane holds row|col = lane&31, k = (lane>>5)*8+j;
// per-frag b128 read at row = frag*32 + (lane&31), byte = (ks*32 + (lane>>5)*16)
// ^ ((lane&7)<<4). All 24 reads/tile = 8 persistent address VGPRs (offA/offB per
// ks; wave-uniform half-bases folded into the 16-bit imm) + `^= 65536` per tile.
// C/D map: col = lane&31, row = (reg&3) + 8*(reg>>2) + 4*(lane>>5)  [m74/m101].
//
// Per tile t (c=t&1): top: stage(t+1) -> c^1 (8 gloads via persistent ptrs);
//   ks0..ks2: prefetch frags(ks+1); setprio(1); 8 MFMA(ks); setprio(0)
//   sync:     lgkmcnt(0); vmcnt(0); BARRIER   [stage(t+1) landed; buf c reads done]
//   ks3:      toggle offs; prefetch next-tile frags(ks0) from c^1; 8 MFMA(ks3)
// Hazard ledger: stage at top of t+1 overwrites buf c — every wave's buf-c reads
// completed before t's lgkmcnt(0)+BARRIER ✓; phase-3 reads of c^1 follow the
// vmcnt(0)+BARRIER that guarantees all waves' stage(t+1) landed ✓.
__global__ __launch_bounds__(512, 2) void gemm_kernel(const unsigned short* __restrict__ A,
                                                      const unsigned short* __restrict__ W,
                                                      const float* __restrict__ bias,
                                                      float* __restrict__ C) {
    extern __shared__ char lds[];
    const int tid  = threadIdx.x;
    const int wave = tid >> 6;
    const int lane = tid & 63;
    const int l31  = lane & 31;
    const int lhi  = lane >> 5;
    const int wr   = wave >> 2;   // 0..1 -> 128-row band
    const int wc   = wave & 3;    // 0..3 -> 64-col band

    // T1: XCD swizzle. nwg=1024 (%8==0); each XCD: 2 M-rows x all N -> A panel L2-hot.
    const int bid = blockIdx.x;
    const int wg  = ((bid & 7) << 7) | (bid >> 3);
    const int rowBase = (wg >> 6) * BM;
    const int colBase = (wg & 63) * BN;

    f32x16 acc[4][2] = {};   // 128 AGPRs (unified file)

    // persistent ds-read address VGPRs (buf 0); toggle ^=65536 per tile
    uint32_t offA[4], offB[4];
#pragma unroll
    for (int ks = 0; ks < 4; ++ks) {
        const uint32_t colb = ((uint32_t)(ks * 32 + (lhi << 4))) ^ ((uint32_t)(lane & 7) << 4);
        offA[ks] = (uint32_t)(wr * 16384) + ((uint32_t)l31 << 7) + colb;
        offB[ks] = 32768u + (uint32_t)((wc >> 1) * 16384) + ((uint32_t)l31 << 7) + colb;
    }
    const uint32_t brB = (uint32_t)((wc & 1) * 64 * 128);  // B row-band imm addend (64 rows)

    // persistent staging source pointers (advance += BK per tile)
    const unsigned short* sp[8];
#pragma unroll
    for (int u = 0; u < 4; ++u) {
        const unsigned short* g = (u < 2) ? A : W;
        const int rb0 = ((u < 2) ? rowBase : colBase) + (u & 1) * 128;
#pragma unroll
        for (int sub = 0; sub < 2; ++sub) {
            const int Ld   = (sub * 512 + tid) * 16;
            const int r    = Ld >> 7;
            const int colb = (Ld & 127) ^ ((r & 7) << 4);   // inverse-swz source
            sp[u * 2 + sub] = g + (size_t)(rb0 + r) * K_DIM + (colb >> 1);
        }
    }

    auto stage = [&](int c) {     // 8 gloads into dbuf c, then advance sources
        char* base = lds + c * 65536;
#pragma unroll
        for (int u = 0; u < 4; ++u)
#pragma unroll
            for (int sub = 0; sub < 2; ++sub)
                async_copy16(sp[u * 2 + sub],
                             base + u * 16384 + (sub * 512 + wave * 64) * 16);
#pragma unroll
        for (int i = 0; i < 8; ++i) sp[i] += BK;
    };

    // prologue: stage tile 0, drain, read ks0 fragments
    stage(0);
    asm volatile("s_waitcnt vmcnt(0)" ::: "memory");
    BARRIER();

    bf16x8 aF[2][4], bF[2][2];
#pragma unroll
    for (int m = 0; m < 4; ++m)
        aF[0][m] = *(const bf16x8*)(lds + offA[0] + m * 4096);
#pragma unroll
    for (int n = 0; n < 2; ++n)
        bF[0][n] = *(const bf16x8*)(lds + offB[0] + brB + n * 4096);

    for (int t = 0; t < NT; ++t) {
        if (t + 1 < NT) stage((t + 1) & 1);

        // ---- phases ks=0..2: prefetch(ks+1) then MFMA(ks) ----
#pragma unroll
        for (int ks = 0; ks < 3; ++ks) {
            const int cur = ks & 1, nxt = cur ^ 1;
#pragma unroll
            for (int m = 0; m < 4; ++m)
                aF[nxt][m] = *(const bf16x8*)(lds + offA[ks + 1] + m * 4096);
#pragma unroll
            for (int n = 0; n < 2; ++n)
                bF[nxt][n] = *(const bf16x8*)(lds + offB[ks + 1] + brB + n * 4096);
            __builtin_amdgcn_s_setprio(1);
#pragma unroll
            for (int m = 0; m < 4; ++m)
#pragma unroll
                for (int n = 0; n < 2; ++n)
                    acc[m][n] = __builtin_amdgcn_mfma_f32_32x32x16_bf16(
                        aF[cur][m], bF[cur][n], acc[m][n], 0, 0, 0);
            __builtin_amdgcn_s_setprio(0);
        }

        // ---- single sync point per tile ----
        asm volatile("s_waitcnt lgkmcnt(0)" ::: "memory");
        asm volatile("s_waitcnt vmcnt(0)" ::: "memory");
        BARRIER();
        __builtin_amdgcn_sched_barrier(0);

        // ---- phase ks=3: prefetch next tile's ks0 from other dbuf, MFMA(ks3) ----
        if (t + 1 < NT) {
#pragma unroll
            for (int k2 = 0; k2 < 4; ++k2) { offA[k2] ^= 65536u; offB[k2] ^= 65536u; }
#pragma unroll
            for (int m = 0; m < 4; ++m)
                aF[0][m] = *(const bf16x8*)(lds + offA[0] + m * 4096);
#pragma unroll
            for (int n = 0; n < 2; ++n)
                bF[0][n] = *(const bf16x8*)(lds + offB[0] + brB + n * 4096);
        }
        __builtin_amdgcn_s_setprio(1);
#pragma unroll
        for (int m = 0; m < 4; ++m)
#pragma unroll
            for (int n = 0; n < 2; ++n)
                acc[m][n] = __builtin_amdgcn_mfma_f32_32x32x16_bf16(
                    aF[1][m], bF[1][n], acc[m][n], 0, 0, 0);
        __builtin_amdgcn_s_setprio(0);
    }

    // epilogue: 32x32 C/D map col=lane&31, row=(reg&3)+8*(reg>>2)+4*(lane>>5)
#pragma unroll
    for (int m = 0; m < 4; ++m)
#pragma unroll
        for (int n = 0; n < 2; ++n) {
            const int gcol = colBase + wc * 64 + n * 32 + l31;
            const float bv = bias[gcol];
#pragma unroll
            for (int r = 0; r < 16; ++r) {
                const int grow = rowBase + wr * 128 + m * 32 +
                                 (r & 3) + 8 * (r >> 2) + 4 * lhi;
                C[(size_t)grow * N_DIM + gcol] = acc[m][n][r] + bv;
            }
        }
}

extern "C" void kernel_launch(void* const* d_in, const int* in_sizes, int n_in,
                              void* d_out, int out_size, void* d_ws, size_t ws_size,
                              hipStream_t stream) {
    const float* x       = (const float*)d_in[0];
    const int*   stored  = (const int*)d_in[1];
    const int*   sign    = (const int*)d_in[2];
    const float* log_min = (const float*)d_in[3];
    const float* log_max = (const float*)d_in[4];
    const float* bias    = (const float*)d_in[5];
    float* out = (float*)d_out;

    unsigned short* Ab = (unsigned short*)d_ws;                         // 32 MB
    unsigned short* Wb = (unsigned short*)((char*)d_ws +
                          (size_t)M_DIM * K_DIM * sizeof(unsigned short)); // +128 MB

    cast_x_kernel<<<2048, 256, 0, stream>>>(x, Ab, (M_DIM * K_DIM) / 8);
    dequant_kernel<<<4096, 256, 0, stream>>>(stored, sign, log_min, log_max, Wb,
                                             (N_DIM * K_DIM) / 8);

    hipFuncSetAttribute((const void*)gemm_kernel,
                        hipFuncAttributeMaxDynamicSharedMemorySize, 131072);
    gemm_kernel<<<dim3((M_DIM / BM) * (N_DIM / BN)), dim3(512), 131072, stream>>>(
        Ab, Wb, bias, out);
}